// Round 11
// baseline (975.039 us; speedup 1.0000x reference)
//
#include <hip/hip_runtime.h>
#include <hip/hip_bf16.h>

#define T_LEN 32768
#define B_N   4
#define RC    32
#define DC    32
#define SC    256
#define OUTC  256
#define NL    40
#define KTOT  (NL * RC)   // 1280
#define NBT   (B_N * T_LEN)
#define SLOTB ((size_t)NBT * 32 * 2)   // 8 MB per stream slot
#define BTW   128                       // bt per k_skipfinal block
#define RING  24576                     // skipfinal ring slot: A 16 KB + B 8 KB

typedef float f32x4 __attribute__((ext_vector_type(4)));
typedef short bf16x8 __attribute__((ext_vector_type(8)));
typedef __attribute__((address_space(3))) unsigned int lds_u32;
typedef __attribute__((address_space(3))) char lds_char;
typedef __attribute__((address_space(1))) unsigned int glb_u32;

// ---------- helpers ----------
__device__ __forceinline__ unsigned short f2bf_bits(float f) {
    __hip_bfloat16 b = __float2bfloat16(f);
    unsigned short u;
    __builtin_memcpy(&u, &b, 2);
    return u;
}
__device__ __forceinline__ unsigned pack2(float a, float b) {
    return (unsigned)f2bf_bits(a) | ((unsigned)f2bf_bits(b) << 16);
}
__device__ __forceinline__ float bflo(unsigned u) { return __uint_as_float((u & 0xFFFFu) << 16); }
__device__ __forceinline__ float bfhi(unsigned u) { return __uint_as_float(u & 0xFFFF0000u); }
__device__ __forceinline__ float ftanh(float x) {
    float e = __expf(2.f * x);
    return 1.f - 2.f / (e + 1.f);
}
// swizzle involution: XOR col bits 4-5 with (row>>1)&3  (row = byte>>6)
__device__ __forceinline__ int swz(int L) { return L ^ ((((L >> 7) & 3)) << 4); }

// ---------- prep: bf16 weight packs + bias sum ----------
__global__ __launch_bounds__(256) void k_prep(const float* __restrict__ Ws,
                                              const float* __restrict__ Wf,
                                              const float* __restrict__ Wd,
                                              const float* __restrict__ Wr,
                                              const float* __restrict__ bs,
                                              unsigned short* __restrict__ Wsk2,
                                              unsigned short* __restrict__ Wfk,
                                              unsigned short* __restrict__ Wd1k,
                                              unsigned short* __restrict__ Wd0k,
                                              unsigned short* __restrict__ Wrk,
                                              float* __restrict__ bs_sum) {
    int g = blockIdx.x * 256 + threadIdx.x;
    if (g < SC * KTOT) {
        int i = g >> 13, r = g & 8191;      // 8192 = 256 oc * 32 c
        int oc = r >> 5, c = r & 31;
        Wsk2[g] = f2bf_bits(Ws[(i * SC + oc) * RC + c]);
        return;
    }
    g -= SC * KTOT;
    if (g < OUTC * SC) { Wfk[g] = f2bf_bits(Wf[g]); return; }
    g -= OUTC * SC;
    if (g < NL * 1024) {
        int i = g >> 10, r = g & 1023;
        int o = r >> 5, c = r & 31;
        Wd1k[g] = f2bf_bits(Wd[((i * DC + o) * RC + c) * 2 + 1]);
        return;
    }
    g -= NL * 1024;
    if (g < NL * 1024) {
        int i = g >> 10, r = g & 1023;
        int o = r >> 5, c = r & 31;
        Wd0k[g] = f2bf_bits(Wd[((i * DC + o) * RC + c) * 2 + 0]);
        return;
    }
    g -= NL * 1024;
    if (g < NL * 1024) { Wrk[g] = f2bf_bits(Wr[g]); return; }
    g -= NL * 1024;
    if (g < SC) {
        float s = 0.f;
        for (int i = 0; i < NL; ++i) s += bs[i * SC + g];
        bs_sum[g] = s;
    }
}

// ---------- start conv -> bf16 stream slot 0 ----------
__global__ __launch_bounds__(256) void k_start(const float* __restrict__ x,
                                               const float* __restrict__ Wst,
                                               const float* __restrict__ bst,
                                               unsigned short* __restrict__ h0) {
    int g = blockIdx.x * 256 + threadIdx.x;   // bt
    float xv = x[g];
    unsigned u[16];
#pragma unroll
    for (int q = 0; q < 16; ++q) {
        float a = Wst[2 * q] * xv + bst[2 * q];
        float b = Wst[2 * q + 1] * xv + bst[2 * q + 1];
        u[q] = pack2(a, b);
    }
    unsigned short* op = h0 + (size_t)g * 32;
#pragma unroll
    for (int q = 0; q < 4; ++q) *(uint4*)&op[q * 8] = *(uint4*)&u[q * 4];
}

// ---------- zero the pipeline flags (graph-replay safe) ----------
__global__ __launch_bounds__(512) void k_zeroflags(int* __restrict__ flags) {
    flags[blockIdx.x * 512 + threadIdx.x] = 0;   // 2048 ints
}

// ---------- all-40-layers persistent pipeline ----------
// Block (c,b) owns t in [c*512, c*512+512) of batch b. Layer i reads slot i
// (own range + left halo <=512), writes slot i+1 own range. Left-neighbor
// producer-consumer via agent-scope acquire/release flags (publish-then-spin).
// Dependency DAG is acyclic (waits only on lower linear block id); grid = 256
// blocks at 1/CU (capacity 2/CU) -> all resident. Bit-identical math to k_layer.
__device__ __forceinline__ void layer_step(const unsigned short* __restrict__ slotin,
                                           unsigned short* __restrict__ slotout,
                                           const unsigned short* __restrict__ w1p,
                                           const unsigned short* __restrict__ w0p,
                                           const unsigned short* __restrict__ wrp,
                                           const float* __restrict__ bdp,
                                           const float* __restrict__ brp,
                                           unsigned short* zp, int tbase, int b,
                                           int lr, int lg, int d) {
    bf16x8 wd1[2], wd0[2], wr[2];
    float4 bdv[2], brv[2];
#pragma unroll
    for (int m = 0; m < 2; ++m) {
        int ao = (m * 16 + lr) * 32 + 8 * lg;
        wd1[m] = *(const bf16x8*)(w1p + ao);
        wd0[m] = *(const bf16x8*)(w0p + ao);
        wr[m]  = *(const bf16x8*)(wrp + ao);
        bdv[m] = *(const float4*)(bdp + m * 16 + 4 * lg);
        brv[m] = *(const float4*)(brp + m * 16 + 4 * lg);
    }
#pragma unroll
    for (int n = 0; n < 4; ++n) {
        int t = tbase + n * 16 + lr;
        size_t bt = ((size_t)b << 15) + t;
        const unsigned short* hp = slotin + bt * 32;
        bf16x8 hc = *(const bf16x8*)(hp + 8 * lg);
        uint2 hcc0 = *(const uint2*)(hp + 4 * lg);
        uint2 hcc1 = *(const uint2*)(hp + 16 + 4 * lg);
        bf16x8 hs = (bf16x8){0, 0, 0, 0, 0, 0, 0, 0};
        if (t >= d) hs = *(const bf16x8*)(hp - (size_t)d * 32 + 8 * lg);

        f32x4 z0 = __builtin_amdgcn_mfma_f32_16x16x32_bf16(wd0[0], hs, (f32x4){0.f, 0.f, 0.f, 0.f}, 0, 0, 0);
        z0 = __builtin_amdgcn_mfma_f32_16x16x32_bf16(wd1[0], hc, z0, 0, 0, 0);
        f32x4 z1 = __builtin_amdgcn_mfma_f32_16x16x32_bf16(wd0[1], hs, (f32x4){0.f, 0.f, 0.f, 0.f}, 0, 0, 0);
        z1 = __builtin_amdgcn_mfma_f32_16x16x32_bf16(wd1[1], hc, z1, 0, 0, 0);

        uint2 u0, u1;
        u0.x = pack2(ftanh(z0[0] + bdv[0].x), ftanh(z0[1] + bdv[0].y));
        u0.y = pack2(ftanh(z0[2] + bdv[0].z), ftanh(z0[3] + bdv[0].w));
        u1.x = pack2(ftanh(z1[0] + bdv[1].x), ftanh(z1[1] + bdv[1].y));
        u1.y = pack2(ftanh(z1[2] + bdv[1].z), ftanh(z1[3] + bdv[1].w));
        *(uint2*)(zp + lr * 40 + 4 * lg) = u0;
        *(uint2*)(zp + lr * 40 + 16 + 4 * lg) = u1;

        bf16x8 zb = *(const bf16x8*)(zp + lr * 40 + 8 * lg);
        f32x4 r0 = __builtin_amdgcn_mfma_f32_16x16x32_bf16(wr[0], zb, (f32x4){0.f, 0.f, 0.f, 0.f}, 0, 0, 0);
        f32x4 r1 = __builtin_amdgcn_mfma_f32_16x16x32_bf16(wr[1], zb, (f32x4){0.f, 0.f, 0.f, 0.f}, 0, 0, 0);

        uint2 o0, o1;
        o0.x = pack2(bflo(hcc0.x) + r0[0] + brv[0].x, bfhi(hcc0.x) + r0[1] + brv[0].y);
        o0.y = pack2(bflo(hcc0.y) + r0[2] + brv[0].z, bfhi(hcc0.y) + r0[3] + brv[0].w);
        o1.x = pack2(bflo(hcc1.x) + r1[0] + brv[1].x, bfhi(hcc1.x) + r1[1] + brv[1].y);
        o1.y = pack2(bflo(hcc1.y) + r1[2] + brv[1].z, bfhi(hcc1.y) + r1[3] + brv[1].w);
        unsigned short* op = slotout + bt * 32;
        *(uint2*)(op + 4 * lg) = o0;
        *(uint2*)(op + 16 + 4 * lg) = o1;
    }
}

__global__ __launch_bounds__(512, 2) void k_pipe(const unsigned short* __restrict__ slot0,
                                                 unsigned short* __restrict__ S1h,
                                                 const unsigned short* __restrict__ Wd1k,
                                                 const unsigned short* __restrict__ Wd0k,
                                                 const unsigned short* __restrict__ Wrk,
                                                 const float* __restrict__ bd,
                                                 const float* __restrict__ br,
                                                 int* __restrict__ flags) {
    __shared__ unsigned short zbuf[8][16 * 40];   // per-wave z tile (16 bt x 40)
    const int tid = threadIdx.x;
    const int lane = tid & 63, wq = tid >> 6;
    const int lr = lane & 15, lg = lane >> 4;
    const int c = blockIdx.x, b = blockIdx.y;
    const int blk = b * 64 + c;
    unsigned short* zp = &zbuf[wq][0];
    const int tbase = c * 512 + wq * 64;
    const size_t SLOTE = SLOTB / 2;   // slot stride in elements

    // layer 0: input slot0, no dependency
    layer_step(slot0, S1h, Wd1k, Wd0k, Wrk, bd, br, zp, tbase, b, lr, lg, 1);
    __syncthreads();
    if (tid == 0) {
        __hip_atomic_store(flags + blk * 8, 1, __ATOMIC_RELEASE, __HIP_MEMORY_SCOPE_AGENT);
        if (c > 0) {
            while (__hip_atomic_load(flags + (blk - 1) * 8, __ATOMIC_ACQUIRE, __HIP_MEMORY_SCOPE_AGENT) < 1)
                __builtin_amdgcn_s_sleep(2);
        }
    }
    __syncthreads();

    for (int i = 1; i < NL; ++i) {
        int d = 1 << (i % 10);
        layer_step(S1h + (size_t)(i - 1) * SLOTE, S1h + (size_t)i * SLOTE,
                   Wd1k + i * 1024, Wd0k + i * 1024, Wrk + i * 1024,
                   bd + i * DC, br + i * RC, zp, tbase, b, lr, lg, d);
        __syncthreads();
        if (tid == 0 && i < NL - 1) {
            __hip_atomic_store(flags + blk * 8, i + 1, __ATOMIC_RELEASE, __HIP_MEMORY_SCOPE_AGENT);
            if (c > 0) {
                while (__hip_atomic_load(flags + (blk - 1) * 8, __ATOMIC_ACQUIRE, __HIP_MEMORY_SCOPE_AGENT) < i + 1)
                    __builtin_amdgcn_s_sleep(2);
            }
        }
        __syncthreads();
    }
}

// ---------- fused skip + final GEMM (R8 version, verbatim: 150 us measured) ----------
__global__ __launch_bounds__(512, 4) void k_skipfinal(const unsigned short* __restrict__ hist,
                                                      const unsigned short* __restrict__ Wsk2,
                                                      const unsigned short* __restrict__ Wfk,
                                                      const float* __restrict__ bs_sum,
                                                      const float* __restrict__ bfv,
                                                      float* __restrict__ outp) {
    __shared__ char smem[65536];   // ring: 2 x 24 KB ; phase-2 sk tile 64 KB overlays
    const int tid = threadIdx.x;
    const int lane = tid & 63, wq = tid >> 6;
    const int lr = lane & 15, lg = lane >> 4;
    const int wm = wq & 3, wn = wq >> 2;
    const int bt0 = blockIdx.x * BTW;
    const char* histb = (const char*)hist;
    const char* Wsb = (const char*)Wsk2;
    lds_char* smem3 = (lds_char*)smem;

    int asrc[2], bsrc;
#pragma unroll
    for (int p = 0; p < 2; ++p) asrc[p] = swz(p * 8192 + tid * 16);
    {
        int D = tid * 16;
        bsrc = bt0 * 64 + swz(D);
    }

    auto stage = [&](int k) {
        char* base = smem + (k & 1) * RING;
#pragma unroll
        for (int p = 0; p < 2; ++p)
            __builtin_amdgcn_global_load_lds((const glb_u32*)(Wsb + (size_t)k * 16384 + asrc[p]),
                                             (lds_u32*)(base + p * 8192 + tid * 16), 16, 0, 0);
        __builtin_amdgcn_global_load_lds((const glb_u32*)(histb + (size_t)k * SLOTB + bsrc),
                                         (lds_u32*)(base + 16384 + tid * 16), 16, 0, 0);
    };

    f32x4 acc[4][4];
#pragma unroll
    for (int m = 0; m < 4; ++m)
#pragma unroll
        for (int n = 0; n < 4; ++n) acc[m][n] = (f32x4){0.f, 0.f, 0.f, 0.f};

    const int cswz = (lg * 16) ^ (((lr >> 1) & 3) << 4);
    const int arow = wm * 64 + lr;
    const int brow = wn * 64 + lr;

    stage(0);
    stage(1);

#pragma unroll
    for (int i = 0; i < NL; ++i) {
        if (i >= 1 && i + 1 < NL) stage(i + 1);
        if (i + 1 < NL) asm volatile("s_waitcnt vmcnt(3)" ::: "memory");
        else            asm volatile("s_waitcnt vmcnt(0)" ::: "memory");
        __builtin_amdgcn_s_barrier();

        lds_char* Ab = smem3 + (i & 1) * RING;
        lds_char* Bb = Ab + 16384;
        bf16x8 af0, af1, af2, af3, bb0, bb1, bb2, bb3;
        asm volatile("ds_read_b128 %0, %1" : "=v"(af0) : "v"(Ab + (arow + 0) * 64 + cswz));
        asm volatile("ds_read_b128 %0, %1" : "=v"(af1) : "v"(Ab + (arow + 16) * 64 + cswz));
        asm volatile("ds_read_b128 %0, %1" : "=v"(af2) : "v"(Ab + (arow + 32) * 64 + cswz));
        asm volatile("ds_read_b128 %0, %1" : "=v"(af3) : "v"(Ab + (arow + 48) * 64 + cswz));
        asm volatile("ds_read_b128 %0, %1" : "=v"(bb0) : "v"(Bb + (brow + 0) * 64 + cswz));
        asm volatile("ds_read_b128 %0, %1" : "=v"(bb1) : "v"(Bb + (brow + 16) * 64 + cswz));
        asm volatile("ds_read_b128 %0, %1" : "=v"(bb2) : "v"(Bb + (brow + 32) * 64 + cswz));
        asm volatile("ds_read_b128 %0, %1" : "=v"(bb3) : "v"(Bb + (brow + 48) * 64 + cswz));
        asm volatile("s_waitcnt lgkmcnt(0)" ::: "memory");
        __builtin_amdgcn_sched_barrier(0);

        acc[0][0] = __builtin_amdgcn_mfma_f32_16x16x32_bf16(af0, bb0, acc[0][0], 0, 0, 0);
        acc[1][0] = __builtin_amdgcn_mfma_f32_16x16x32_bf16(af1, bb0, acc[1][0], 0, 0, 0);
        acc[2][0] = __builtin_amdgcn_mfma_f32_16x16x32_bf16(af2, bb0, acc[2][0], 0, 0, 0);
        acc[3][0] = __builtin_amdgcn_mfma_f32_16x16x32_bf16(af3, bb0, acc[3][0], 0, 0, 0);
        acc[0][1] = __builtin_amdgcn_mfma_f32_16x16x32_bf16(af0, bb1, acc[0][1], 0, 0, 0);
        acc[1][1] = __builtin_amdgcn_mfma_f32_16x16x32_bf16(af1, bb1, acc[1][1], 0, 0, 0);
        acc[2][1] = __builtin_amdgcn_mfma_f32_16x16x32_bf16(af2, bb1, acc[2][1], 0, 0, 0);
        acc[3][1] = __builtin_amdgcn_mfma_f32_16x16x32_bf16(af3, bb1, acc[3][1], 0, 0, 0);
        acc[0][2] = __builtin_amdgcn_mfma_f32_16x16x32_bf16(af0, bb2, acc[0][2], 0, 0, 0);
        acc[1][2] = __builtin_amdgcn_mfma_f32_16x16x32_bf16(af1, bb2, acc[1][2], 0, 0, 0);
        acc[2][2] = __builtin_amdgcn_mfma_f32_16x16x32_bf16(af2, bb2, acc[2][2], 0, 0, 0);
        acc[3][2] = __builtin_amdgcn_mfma_f32_16x16x32_bf16(af3, bb2, acc[3][2], 0, 0, 0);
        acc[0][3] = __builtin_amdgcn_mfma_f32_16x16x32_bf16(af0, bb3, acc[0][3], 0, 0, 0);
        acc[1][3] = __builtin_amdgcn_mfma_f32_16x16x32_bf16(af1, bb3, acc[1][3], 0, 0, 0);
        acc[2][3] = __builtin_amdgcn_mfma_f32_16x16x32_bf16(af2, bb3, acc[2][3], 0, 0, 0);
        acc[3][3] = __builtin_amdgcn_mfma_f32_16x16x32_bf16(af3, bb3, acc[3][3], 0, 0, 0);
        __builtin_amdgcn_s_barrier();
    }
    __syncthreads();

    char* skb = smem;
#pragma unroll
    for (int m = 0; m < 4; ++m) {
        int oc0 = wm * 64 + m * 16 + lg * 4;
        float c0 = bs_sum[oc0], c1 = bs_sum[oc0 + 1], c2 = bs_sum[oc0 + 2], c3 = bs_sum[oc0 + 3];
#pragma unroll
        for (int n = 0; n < 4; ++n) {
            int bt = wn * 64 + n * 16 + lr;
            f32x4 v = acc[m][n];
            uint2 u;
            u.x = pack2(fmaxf(v[0] + c0, 0.f), fmaxf(v[1] + c1, 0.f));
            u.y = pack2(fmaxf(v[2] + c2, 0.f), fmaxf(v[3] + c3, 0.f));
            int L = bt * 512 + oc0 * 2;
            *(uint2*)(skb + (L ^ ((bt & 7) << 4))) = u;
        }
    }
    __syncthreads();

    f32x4 acc2[4][4];
#pragma unroll
    for (int m = 0; m < 4; ++m)
#pragma unroll
        for (int n = 0; n < 4; ++n) acc2[m][n] = (f32x4){0.f, 0.f, 0.f, 0.f};

    const unsigned short* Fb = Wfk + (size_t)(wm * 64 + lr) * SC + 8 * lg;

#pragma unroll
    for (int kk = 0; kk < SC / 32; ++kk) {
        bf16x8 fa[4];
#pragma unroll
        for (int m = 0; m < 4; ++m) fa[m] = *(const bf16x8*)(Fb + (size_t)m * 16 * SC + kk * 32);
        bf16x8 sbv[4];
#pragma unroll
        for (int n = 0; n < 4; ++n) {
            int bt = wn * 64 + n * 16 + lr;
            int L = bt * 512 + kk * 64 + lg * 16;
            sbv[n] = *(const bf16x8*)(skb + (L ^ ((bt & 7) << 4)));
        }
#pragma unroll
        for (int m = 0; m < 4; ++m)
#pragma unroll
            for (int n = 0; n < 4; ++n)
                acc2[m][n] = __builtin_amdgcn_mfma_f32_16x16x32_bf16(fa[m], sbv[n], acc2[m][n], 0, 0, 0);
    }

    int b2 = bt0 >> 15;
    int t0 = bt0 & (T_LEN - 1);
#pragma unroll
    for (int m = 0; m < 4; ++m) {
        int o0 = wm * 64 + m * 16 + lg * 4;
        float q0 = bfv[o0], q1 = bfv[o0 + 1], q2 = bfv[o0 + 2], q3 = bfv[o0 + 3];
#pragma unroll
        for (int n = 0; n < 4; ++n) {
            int t = t0 + wn * 64 + n * 16 + lr;
            f32x4 v = acc2[m][n];
            outp[((size_t)(b2 * OUTC + o0 + 0) << 15) + t] = v[0] + q0;
            outp[((size_t)(b2 * OUTC + o0 + 1) << 15) + t] = v[1] + q1;
            outp[((size_t)(b2 * OUTC + o0 + 2) << 15) + t] = v[2] + q2;
            outp[((size_t)(b2 * OUTC + o0 + 3) << 15) + t] = v[3] + q3;
        }
    }
}

extern "C" void kernel_launch(void* const* d_in, const int* in_sizes, int n_in,
                              void* d_out, int out_size, void* d_ws, size_t ws_size,
                              hipStream_t stream) {
    const float* x       = (const float*)d_in[0];
    const float* W_start = (const float*)d_in[1];
    const float* b_start = (const float*)d_in[2];
    const float* Wd      = (const float*)d_in[3];
    const float* bd      = (const float*)d_in[4];
    const float* Wr      = (const float*)d_in[5];
    const float* br      = (const float*)d_in[6];
    const float* Ws      = (const float*)d_in[7];
    const float* bs      = (const float*)d_in[8];
    const float* Wf      = (const float*)d_in[9];
    const float* bfv     = (const float*)d_in[10];

    char* wsb = (char*)d_ws;
    unsigned short* Wsk2 = (unsigned short*)(wsb);                      // 655360 B
    unsigned short* Wfk  = (unsigned short*)(wsb + 655360);             // 131072 B
    unsigned short* Wd1k = (unsigned short*)(wsb + 786432);             // 81920 B
    unsigned short* Wd0k = (unsigned short*)(wsb + 868352);             // 81920 B
    unsigned short* Wrk  = (unsigned short*)(wsb + 950272);             // 81920 B
    float*          bs_sum = (float*)(wsb + 1032192);                   // 1024 B
    int*            flags  = (int*)(wsb + 1033216);                     // 8192 B (256 x 8 ints)
    char* S1 = wsb + (1 << 20);            // stream slots 1..40 (= hist layers 0..39)
    char* X  = S1 + 40 * SLOTB;            // slot 0

    k_prep<<<(SC * KTOT + OUTC * SC + 3 * NL * 1024 + SC + 255) / 256, 256, 0, stream>>>(
        Ws, Wf, Wd, Wr, bs, Wsk2, Wfk, Wd1k, Wd0k, Wrk, bs_sum);
    k_start<<<NBT / 256, 256, 0, stream>>>(x, W_start, b_start, (unsigned short*)X);
    k_zeroflags<<<4, 512, 0, stream>>>(flags);

    dim3 gp(T_LEN / 512, B_N);
    k_pipe<<<gp, 512, 0, stream>>>((const unsigned short*)X, (unsigned short*)S1,
                                   Wd1k, Wd0k, Wrk, bd, br, flags);

    k_skipfinal<<<NBT / BTW, 512, 0, stream>>>((unsigned short*)S1, Wsk2, Wfk, bs_sum, bfv, (float*)d_out);
}

// Round 12
// 755.853 us; speedup vs baseline: 1.2900x; 1.2900x over previous
//
#include <hip/hip_runtime.h>
#include <hip/hip_bf16.h>

#define T_LEN 32768
#define B_N   4
#define RC    32
#define DC    32
#define SC    256
#define OUTC  256
#define NL    40
#define KTOT  (NL * RC)   // 1280
#define NBT   (B_N * T_LEN)
#define SLOTB ((size_t)NBT * 32 * 2)   // 8 MB per stream slot
#define SLOTE ((size_t)NBT * 32)       // slot stride in elements
#define BTW   128                       // bt per k_skipfinal block
#define RING  24576                     // skipfinal ring slot: A 16 KB + B 8 KB
#define GT    1536                      // group LDS buffer extent (t)

typedef float f32x4 __attribute__((ext_vector_type(4)));
typedef short bf16x8 __attribute__((ext_vector_type(8)));
typedef __attribute__((address_space(3))) unsigned int lds_u32;
typedef __attribute__((address_space(3))) char lds_char;
typedef __attribute__((address_space(1))) unsigned int glb_u32;

// ---------- helpers ----------
__device__ __forceinline__ unsigned short f2bf_bits(float f) {
    __hip_bfloat16 b = __float2bfloat16(f);
    unsigned short u;
    __builtin_memcpy(&u, &b, 2);
    return u;
}
__device__ __forceinline__ unsigned pack2(float a, float b) {
    return (unsigned)f2bf_bits(a) | ((unsigned)f2bf_bits(b) << 16);
}
__device__ __forceinline__ float bflo(unsigned u) { return __uint_as_float((u & 0xFFFFu) << 16); }
__device__ __forceinline__ float bfhi(unsigned u) { return __uint_as_float(u & 0xFFFF0000u); }
__device__ __forceinline__ float ftanh(float x) {
    float e = __expf(2.f * x);
    return 1.f - 2.f / (e + 1.f);
}
// skipfinal swizzle (unchanged, R8)
__device__ __forceinline__ int swz(int L) { return L ^ ((((L >> 7) & 3)) << 4); }
// group-buffer swizzle: col byte XOR from u (involution, consistent read/write)
__device__ __forceinline__ int lcol(int u, int colbyte) {
    return colbyte ^ (((u ^ (u >> 2)) & 3) << 4);
}

// ---------- prep: bf16 weight packs + bias sum (unchanged) ----------
__global__ __launch_bounds__(256) void k_prep(const float* __restrict__ Ws,
                                              const float* __restrict__ Wf,
                                              const float* __restrict__ Wd,
                                              const float* __restrict__ Wr,
                                              const float* __restrict__ bs,
                                              unsigned short* __restrict__ Wsk2,
                                              unsigned short* __restrict__ Wfk,
                                              unsigned short* __restrict__ Wd1k,
                                              unsigned short* __restrict__ Wd0k,
                                              unsigned short* __restrict__ Wrk,
                                              float* __restrict__ bs_sum) {
    int g = blockIdx.x * 256 + threadIdx.x;
    if (g < SC * KTOT) {
        int i = g >> 13, r = g & 8191;
        int oc = r >> 5, c = r & 31;
        Wsk2[g] = f2bf_bits(Ws[(i * SC + oc) * RC + c]);
        return;
    }
    g -= SC * KTOT;
    if (g < OUTC * SC) { Wfk[g] = f2bf_bits(Wf[g]); return; }
    g -= OUTC * SC;
    if (g < NL * 1024) {
        int i = g >> 10, r = g & 1023;
        int o = r >> 5, c = r & 31;
        Wd1k[g] = f2bf_bits(Wd[((i * DC + o) * RC + c) * 2 + 1]);
        return;
    }
    g -= NL * 1024;
    if (g < NL * 1024) {
        int i = g >> 10, r = g & 1023;
        int o = r >> 5, c = r & 31;
        Wd0k[g] = f2bf_bits(Wd[((i * DC + o) * RC + c) * 2 + 0]);
        return;
    }
    g -= NL * 1024;
    if (g < NL * 1024) { Wrk[g] = f2bf_bits(Wr[g]); return; }
    g -= NL * 1024;
    if (g < SC) {
        float s = 0.f;
        for (int i = 0; i < NL; ++i) s += bs[i * SC + g];
        bs_sum[g] = s;
    }
}

// ---------- start conv -> bf16 stream slot "-1" (unchanged) ----------
__global__ __launch_bounds__(256) void k_start(const float* __restrict__ x,
                                               const float* __restrict__ Wst,
                                               const float* __restrict__ bst,
                                               unsigned short* __restrict__ h0) {
    int g = blockIdx.x * 256 + threadIdx.x;
    float xv = x[g];
    unsigned u[16];
#pragma unroll
    for (int q = 0; q < 16; ++q) {
        float a = Wst[2 * q] * xv + bst[2 * q];
        float b = Wst[2 * q + 1] * xv + bst[2 * q + 1];
        u[q] = pack2(a, b);
    }
    unsigned short* op = h0 + (size_t)g * 32;
#pragma unroll
    for (int q = 0; q < 4; ++q) *(uint4*)&op[q * 8] = *(uint4*)&u[q * 4];
}

// ---------- one layer inside a dilation group (in-place LDS buffer) ----------
// NT = tiles per wave (3 for layers 0-7, 2 for layer 8, 1 for layer 9).
// Layer computes u in [GT - NT*512, GT); owned output = tile p == NT-1 (u >= 1024).
// Phase 1: read hs (may cross tiles) to regs; sync; Phase 2: read hc/hcc (own tile,
// pre-overwrite), compute, write hbuf in place + owned global store; sync.
template<int NT>
__device__ __forceinline__ void group_layer(unsigned short* hbuf,
                                            unsigned short* zp,
                                            const unsigned short* __restrict__ w1g,
                                            const unsigned short* __restrict__ w0g,
                                            const unsigned short* __restrict__ wrg,
                                            const float* __restrict__ bdp,
                                            const float* __restrict__ brp,
                                            unsigned short* __restrict__ slotj,
                                            int t0, int b, int wq, int lr, int lg, int d) {
    bf16x8 wd1[2], wd0[2], wr[2];
    float4 bdv[2], brv[2];
#pragma unroll
    for (int m = 0; m < 2; ++m) {
        int ao = (m * 16 + lr) * 32 + 8 * lg;
        wd1[m] = *(const bf16x8*)(w1g + ao);
        wd0[m] = *(const bf16x8*)(w0g + ao);
        wr[m]  = *(const bf16x8*)(wrg + ao);
        bdv[m] = *(const float4*)(bdp + m * 16 + 4 * lg);
        brv[m] = *(const float4*)(brp + m * 16 + 4 * lg);
    }
    const int u0 = GT - (NT << 9);

    // phase 1: shifted-input frags (cross-tile reads) -> regs
    bf16x8 hs[NT][2];
#pragma unroll
    for (int p = 0; p < NT; ++p) {
        int ut = u0 + (wq + (p << 4)) * 32;
#pragma unroll
        for (int n = 0; n < 2; ++n) {
            int u = ut + n * 16 + lr;
            int t = t0 + u - 1024;
            int us = u - d; if (us < 0) us = 0;
            bf16x8 v = *(const bf16x8*)((const char*)hbuf + us * 64 + lcol(us, lg * 16));
            if (t < d) v = (bf16x8){0, 0, 0, 0, 0, 0, 0, 0};
            hs[p][n] = v;
        }
    }
    __syncthreads();

    // phase 2: per-tile compute + in-place write
#pragma unroll
    for (int p = 0; p < NT; ++p) {
        const int ut = u0 + (wq + (p << 4)) * 32;
        bf16x8 hcv[2];
        uint2 hccv[2][2];
#pragma unroll
        for (int n = 0; n < 2; ++n) {
            int u = ut + n * 16 + lr;
            hcv[n] = *(const bf16x8*)((const char*)hbuf + u * 64 + lcol(u, lg * 16));
#pragma unroll
            for (int m = 0; m < 2; ++m)
                hccv[n][m] = *(const uint2*)((const char*)hbuf + u * 64 + lcol(u, m * 32 + lg * 8));
        }
        f32x4 zac[2][2];
#pragma unroll
        for (int m = 0; m < 2; ++m)
#pragma unroll
            for (int n = 0; n < 2; ++n) {
                f32x4 a = __builtin_amdgcn_mfma_f32_16x16x32_bf16(wd0[m], hs[p][n], (f32x4){0.f, 0.f, 0.f, 0.f}, 0, 0, 0);
                zac[m][n] = __builtin_amdgcn_mfma_f32_16x16x32_bf16(wd1[m], hcv[n], a, 0, 0, 0);
            }
#pragma unroll
        for (int m = 0; m < 2; ++m)
#pragma unroll
            for (int n = 0; n < 2; ++n) {
                int rbt = n * 16 + lr;
                uint2 uu;
                uu.x = pack2(ftanh(zac[m][n][0] + bdv[m].x), ftanh(zac[m][n][1] + bdv[m].y));
                uu.y = pack2(ftanh(zac[m][n][2] + bdv[m].z), ftanh(zac[m][n][3] + bdv[m].w));
                *(uint2*)(zp + rbt * 40 + m * 16 + 4 * lg) = uu;
            }
        f32x4 racc[2][2];
#pragma unroll
        for (int n = 0; n < 2; ++n) {
            bf16x8 zb = *(const bf16x8*)(zp + (n * 16 + lr) * 40 + 8 * lg);
#pragma unroll
            for (int m = 0; m < 2; ++m)
                racc[m][n] = __builtin_amdgcn_mfma_f32_16x16x32_bf16(wr[m], zb, (f32x4){0.f, 0.f, 0.f, 0.f}, 0, 0, 0);
        }
#pragma unroll
        for (int m = 0; m < 2; ++m)
#pragma unroll
            for (int n = 0; n < 2; ++n) {
                int u = ut + n * 16 + lr;
                uint2 o;
                o.x = pack2(bflo(hccv[n][m].x) + racc[m][n][0] + brv[m].x,
                            bfhi(hccv[n][m].x) + racc[m][n][1] + brv[m].y);
                o.y = pack2(bflo(hccv[n][m].y) + racc[m][n][2] + brv[m].z,
                            bfhi(hccv[n][m].y) + racc[m][n][3] + brv[m].w);
                *(uint2*)((char*)hbuf + u * 64 + lcol(u, m * 32 + lg * 8)) = o;
                if (p == NT - 1) {
                    int t = t0 + u - 1024;
                    *(uint2*)(slotj + ((size_t)b * T_LEN + t) * 32 + m * 16 + 4 * lg) = o;
                }
            }
    }
    __syncthreads();
}

// ---------- 10-layer dilation group, halo-recompute, no cross-block deps ----------
// Block (c,b): owns t in [c*512, c*512+512). LDS buffer spans [t0-1024, t0+512).
__global__ __launch_bounds__(1024) void k_group(const unsigned short* __restrict__ slot_prev,
                                                unsigned short* __restrict__ slot_base,
                                                const unsigned short* __restrict__ Wd1g,
                                                const unsigned short* __restrict__ Wd0g,
                                                const unsigned short* __restrict__ Wrg,
                                                const float* __restrict__ bdg,
                                                const float* __restrict__ brg) {
    __shared__ unsigned short hbuf[GT * 32];        // 96 KB, swizzled rows
    __shared__ unsigned short zbuf[16][32 * 40];    // 40 KB per-wave z tiles
    const int tid = threadIdx.x;
    const int lane = tid & 63, wq = tid >> 6;
    const int lr = lane & 15, lg = lane >> 4;
    const int t0 = blockIdx.x * 512, b = blockIdx.y;
    unsigned short* zp = &zbuf[wq][0];

    // fill buffer from the group-input slot (coalesced global, swizzled LDS write)
    for (int f = tid; f < GT * 4; f += 1024) {
        int u = f >> 2, part = f & 3;
        int t = t0 + u - 1024;
        uint4 v = {0u, 0u, 0u, 0u};
        if (t >= 0) v = *(const uint4*)(slot_prev + ((size_t)b * T_LEN + t) * 32 + part * 8);
        *(uint4*)((char*)hbuf + u * 64 + lcol(u, part * 16)) = v;
    }
    __syncthreads();

#pragma unroll 1
    for (int j = 0; j < 8; ++j)
        group_layer<3>(hbuf, zp, Wd1g + j * 1024, Wd0g + j * 1024, Wrg + j * 1024,
                       bdg + j * 32, brg + j * 32,
                       slot_base + (size_t)j * SLOTE, t0, b, wq, lr, lg, 1 << j);
    group_layer<2>(hbuf, zp, Wd1g + 8 * 1024, Wd0g + 8 * 1024, Wrg + 8 * 1024,
                   bdg + 8 * 32, brg + 8 * 32,
                   slot_base + (size_t)8 * SLOTE, t0, b, wq, lr, lg, 256);
    group_layer<1>(hbuf, zp, Wd1g + 9 * 1024, Wd0g + 9 * 1024, Wrg + 9 * 1024,
                   bdg + 9 * 32, brg + 9 * 32,
                   slot_base + (size_t)9 * SLOTE, t0, b, wq, lr, lg, 512);
}

// ---------- fused skip + final GEMM (R8 version, verbatim: 150 us measured) ----------
__global__ __launch_bounds__(512, 4) void k_skipfinal(const unsigned short* __restrict__ hist,
                                                      const unsigned short* __restrict__ Wsk2,
                                                      const unsigned short* __restrict__ Wfk,
                                                      const float* __restrict__ bs_sum,
                                                      const float* __restrict__ bfv,
                                                      float* __restrict__ outp) {
    __shared__ char smem[65536];
    const int tid = threadIdx.x;
    const int lane = tid & 63, wq = tid >> 6;
    const int lr = lane & 15, lg = lane >> 4;
    const int wm = wq & 3, wn = wq >> 2;
    const int bt0 = blockIdx.x * BTW;
    const char* histb = (const char*)hist;
    const char* Wsb = (const char*)Wsk2;
    lds_char* smem3 = (lds_char*)smem;

    int asrc[2], bsrc;
#pragma unroll
    for (int p = 0; p < 2; ++p) asrc[p] = swz(p * 8192 + tid * 16);
    {
        int D = tid * 16;
        bsrc = bt0 * 64 + swz(D);
    }

    auto stage = [&](int k) {
        char* base = smem + (k & 1) * RING;
#pragma unroll
        for (int p = 0; p < 2; ++p)
            __builtin_amdgcn_global_load_lds((const glb_u32*)(Wsb + (size_t)k * 16384 + asrc[p]),
                                             (lds_u32*)(base + p * 8192 + tid * 16), 16, 0, 0);
        __builtin_amdgcn_global_load_lds((const glb_u32*)(histb + (size_t)k * SLOTB + bsrc),
                                         (lds_u32*)(base + 16384 + tid * 16), 16, 0, 0);
    };

    f32x4 acc[4][4];
#pragma unroll
    for (int m = 0; m < 4; ++m)
#pragma unroll
        for (int n = 0; n < 4; ++n) acc[m][n] = (f32x4){0.f, 0.f, 0.f, 0.f};

    const int cswz = (lg * 16) ^ (((lr >> 1) & 3) << 4);
    const int arow = wm * 64 + lr;
    const int brow = wn * 64 + lr;

    stage(0);
    stage(1);

#pragma unroll
    for (int i = 0; i < NL; ++i) {
        if (i >= 1 && i + 1 < NL) stage(i + 1);
        if (i + 1 < NL) asm volatile("s_waitcnt vmcnt(3)" ::: "memory");
        else            asm volatile("s_waitcnt vmcnt(0)" ::: "memory");
        __builtin_amdgcn_s_barrier();

        lds_char* Ab = smem3 + (i & 1) * RING;
        lds_char* Bb = Ab + 16384;
        bf16x8 af0, af1, af2, af3, bb0, bb1, bb2, bb3;
        asm volatile("ds_read_b128 %0, %1" : "=v"(af0) : "v"(Ab + (arow + 0) * 64 + cswz));
        asm volatile("ds_read_b128 %0, %1" : "=v"(af1) : "v"(Ab + (arow + 16) * 64 + cswz));
        asm volatile("ds_read_b128 %0, %1" : "=v"(af2) : "v"(Ab + (arow + 32) * 64 + cswz));
        asm volatile("ds_read_b128 %0, %1" : "=v"(af3) : "v"(Ab + (arow + 48) * 64 + cswz));
        asm volatile("ds_read_b128 %0, %1" : "=v"(bb0) : "v"(Bb + (brow + 0) * 64 + cswz));
        asm volatile("ds_read_b128 %0, %1" : "=v"(bb1) : "v"(Bb + (brow + 16) * 64 + cswz));
        asm volatile("ds_read_b128 %0, %1" : "=v"(bb2) : "v"(Bb + (brow + 32) * 64 + cswz));
        asm volatile("ds_read_b128 %0, %1" : "=v"(bb3) : "v"(Bb + (brow + 48) * 64 + cswz));
        asm volatile("s_waitcnt lgkmcnt(0)" ::: "memory");
        __builtin_amdgcn_sched_barrier(0);

        acc[0][0] = __builtin_amdgcn_mfma_f32_16x16x32_bf16(af0, bb0, acc[0][0], 0, 0, 0);
        acc[1][0] = __builtin_amdgcn_mfma_f32_16x16x32_bf16(af1, bb0, acc[1][0], 0, 0, 0);
        acc[2][0] = __builtin_amdgcn_mfma_f32_16x16x32_bf16(af2, bb0, acc[2][0], 0, 0, 0);
        acc[3][0] = __builtin_amdgcn_mfma_f32_16x16x32_bf16(af3, bb0, acc[3][0], 0, 0, 0);
        acc[0][1] = __builtin_amdgcn_mfma_f32_16x16x32_bf16(af0, bb1, acc[0][1], 0, 0, 0);
        acc[1][1] = __builtin_amdgcn_mfma_f32_16x16x32_bf16(af1, bb1, acc[1][1], 0, 0, 0);
        acc[2][1] = __builtin_amdgcn_mfma_f32_16x16x32_bf16(af2, bb1, acc[2][1], 0, 0, 0);
        acc[3][1] = __builtin_amdgcn_mfma_f32_16x16x32_bf16(af3, bb1, acc[3][1], 0, 0, 0);
        acc[0][2] = __builtin_amdgcn_mfma_f32_16x16x32_bf16(af0, bb2, acc[0][2], 0, 0, 0);
        acc[1][2] = __builtin_amdgcn_mfma_f32_16x16x32_bf16(af1, bb2, acc[1][2], 0, 0, 0);
        acc[2][2] = __builtin_amdgcn_mfma_f32_16x16x32_bf16(af2, bb2, acc[2][2], 0, 0, 0);
        acc[3][2] = __builtin_amdgcn_mfma_f32_16x16x32_bf16(af3, bb2, acc[3][2], 0, 0, 0);
        acc[0][3] = __builtin_amdgcn_mfma_f32_16x16x32_bf16(af0, bb3, acc[0][3], 0, 0, 0);
        acc[1][3] = __builtin_amdgcn_mfma_f32_16x16x32_bf16(af1, bb3, acc[1][3], 0, 0, 0);
        acc[2][3] = __builtin_amdgcn_mfma_f32_16x16x32_bf16(af2, bb3, acc[2][3], 0, 0, 0);
        acc[3][3] = __builtin_amdgcn_mfma_f32_16x16x32_bf16(af3, bb3, acc[3][3], 0, 0, 0);
        __builtin_amdgcn_s_barrier();
    }
    __syncthreads();

    char* skb = smem;
#pragma unroll
    for (int m = 0; m < 4; ++m) {
        int oc0 = wm * 64 + m * 16 + lg * 4;
        float c0 = bs_sum[oc0], c1 = bs_sum[oc0 + 1], c2 = bs_sum[oc0 + 2], c3 = bs_sum[oc0 + 3];
#pragma unroll
        for (int n = 0; n < 4; ++n) {
            int bt = wn * 64 + n * 16 + lr;
            f32x4 v = acc[m][n];
            uint2 u;
            u.x = pack2(fmaxf(v[0] + c0, 0.f), fmaxf(v[1] + c1, 0.f));
            u.y = pack2(fmaxf(v[2] + c2, 0.f), fmaxf(v[3] + c3, 0.f));
            int L = bt * 512 + oc0 * 2;
            *(uint2*)(skb + (L ^ ((bt & 7) << 4))) = u;
        }
    }
    __syncthreads();

    f32x4 acc2[4][4];
#pragma unroll
    for (int m = 0; m < 4; ++m)
#pragma unroll
        for (int n = 0; n < 4; ++n) acc2[m][n] = (f32x4){0.f, 0.f, 0.f, 0.f};

    const unsigned short* Fb = Wfk + (size_t)(wm * 64 + lr) * SC + 8 * lg;

#pragma unroll
    for (int kk = 0; kk < SC / 32; ++kk) {
        bf16x8 fa[4];
#pragma unroll
        for (int m = 0; m < 4; ++m) fa[m] = *(const bf16x8*)(Fb + (size_t)m * 16 * SC + kk * 32);
        bf16x8 sbv[4];
#pragma unroll
        for (int n = 0; n < 4; ++n) {
            int bt = wn * 64 + n * 16 + lr;
            int L = bt * 512 + kk * 64 + lg * 16;
            sbv[n] = *(const bf16x8*)(skb + (L ^ ((bt & 7) << 4)));
        }
#pragma unroll
        for (int m = 0; m < 4; ++m)
#pragma unroll
            for (int n = 0; n < 4; ++n)
                acc2[m][n] = __builtin_amdgcn_mfma_f32_16x16x32_bf16(fa[m], sbv[n], acc2[m][n], 0, 0, 0);
    }

    int b2 = bt0 >> 15;
    int t0 = bt0 & (T_LEN - 1);
#pragma unroll
    for (int m = 0; m < 4; ++m) {
        int o0 = wm * 64 + m * 16 + lg * 4;
        float q0 = bfv[o0], q1 = bfv[o0 + 1], q2 = bfv[o0 + 2], q3 = bfv[o0 + 3];
#pragma unroll
        for (int n = 0; n < 4; ++n) {
            int t = t0 + wn * 64 + n * 16 + lr;
            f32x4 v = acc2[m][n];
            outp[((size_t)(b2 * OUTC + o0 + 0) << 15) + t] = v[0] + q0;
            outp[((size_t)(b2 * OUTC + o0 + 1) << 15) + t] = v[1] + q1;
            outp[((size_t)(b2 * OUTC + o0 + 2) << 15) + t] = v[2] + q2;
            outp[((size_t)(b2 * OUTC + o0 + 3) << 15) + t] = v[3] + q3;
        }
    }
}

extern "C" void kernel_launch(void* const* d_in, const int* in_sizes, int n_in,
                              void* d_out, int out_size, void* d_ws, size_t ws_size,
                              hipStream_t stream) {
    const float* x       = (const float*)d_in[0];
    const float* W_start = (const float*)d_in[1];
    const float* b_start = (const float*)d_in[2];
    const float* Wd      = (const float*)d_in[3];
    const float* bd      = (const float*)d_in[4];
    const float* Wr      = (const float*)d_in[5];
    const float* br      = (const float*)d_in[6];
    const float* Ws      = (const float*)d_in[7];
    const float* bs      = (const float*)d_in[8];
    const float* Wf      = (const float*)d_in[9];
    const float* bfv     = (const float*)d_in[10];

    char* wsb = (char*)d_ws;
    unsigned short* Wsk2 = (unsigned short*)(wsb);                      // 655360 B
    unsigned short* Wfk  = (unsigned short*)(wsb + 655360);             // 131072 B
    unsigned short* Wd1k = (unsigned short*)(wsb + 786432);             // 81920 B
    unsigned short* Wd0k = (unsigned short*)(wsb + 868352);             // 81920 B
    unsigned short* Wrk  = (unsigned short*)(wsb + 950272);             // 81920 B
    float*          bs_sum = (float*)(wsb + 1032192);                   // 1024 B
    char* S1 = wsb + (1 << 20);            // slots 0..39 (= layer outputs)
    char* X  = S1 + 40 * SLOTB;            // group-0 input (start conv output)

    k_prep<<<(SC * KTOT + OUTC * SC + 3 * NL * 1024 + SC + 255) / 256, 256, 0, stream>>>(
        Ws, Wf, Wd, Wr, bs, Wsk2, Wfk, Wd1k, Wd0k, Wrk, bs_sum);
    k_start<<<NBT / 256, 256, 0, stream>>>(x, W_start, b_start, (unsigned short*)X);

    for (int g = 0; g < 4; ++g) {
        const unsigned short* prev = (g == 0)
            ? (const unsigned short*)X
            : (const unsigned short*)(S1 + (size_t)(10 * g - 1) * SLOTB);
        k_group<<<dim3(T_LEN / 512, B_N), 1024, 0, stream>>>(
            prev, (unsigned short*)(S1 + (size_t)(10 * g) * SLOTB),
            Wd1k + g * 10 * 1024, Wd0k + g * 10 * 1024, Wrk + g * 10 * 1024,
            bd + g * 10 * 32, br + g * 10 * 32);
    }

    k_skipfinal<<<NBT / BTW, 512, 0, stream>>>((unsigned short*)S1, Wsk2, Wfk, bs_sum, bfv, (float*)d_out);
}

// Round 13
// 445.499 us; speedup vs baseline: 2.1886x; 1.6966x over previous
//
#include <hip/hip_runtime.h>
#include <hip/hip_bf16.h>

#define T_LEN 32768
#define B_N   4
#define RC    32
#define DC    32
#define SC    256
#define OUTC  256
#define NL    40
#define KTOT  (NL * RC)   // 1280
#define NBT   (B_N * T_LEN)
#define SLOTB ((size_t)NBT * 32 * 2)   // 8 MB per stream slot
#define BTW   128                       // bt per k_skipfinal block
#define RING  24576                     // ring slot: A 16 KB + B 8 KB

typedef float f32x4 __attribute__((ext_vector_type(4)));
typedef short bf16x8 __attribute__((ext_vector_type(8)));
typedef __attribute__((address_space(3))) unsigned int lds_u32;
typedef __attribute__((address_space(3))) char lds_char;
typedef __attribute__((address_space(1))) unsigned int glb_u32;

// ---------- helpers ----------
__device__ __forceinline__ unsigned short f2bf_bits(float f) {
    __hip_bfloat16 b = __float2bfloat16(f);
    unsigned short u;
    __builtin_memcpy(&u, &b, 2);
    return u;
}
__device__ __forceinline__ unsigned pack2(float a, float b) {
    return (unsigned)f2bf_bits(a) | ((unsigned)f2bf_bits(b) << 16);
}
__device__ __forceinline__ float bflo(unsigned u) { return __uint_as_float((u & 0xFFFFu) << 16); }
__device__ __forceinline__ float bfhi(unsigned u) { return __uint_as_float(u & 0xFFFF0000u); }
__device__ __forceinline__ float ftanh(float x) {
    float e = __expf(2.f * x);
    return 1.f - 2.f / (e + 1.f);
}
// swizzle involution: XOR col bits 4-5 with (row>>1)&3  (row = byte>>6)
__device__ __forceinline__ int swz(int L) { return L ^ ((((L >> 7) & 3)) << 4); }

// ---------- prep: bf16 weight packs + bias sum ----------
__global__ __launch_bounds__(256) void k_prep(const float* __restrict__ Ws,
                                              const float* __restrict__ Wf,
                                              const float* __restrict__ Wd,
                                              const float* __restrict__ Wr,
                                              const float* __restrict__ bs,
                                              unsigned short* __restrict__ Wsk2,
                                              unsigned short* __restrict__ Wfk,
                                              unsigned short* __restrict__ Wd1k,
                                              unsigned short* __restrict__ Wd0k,
                                              unsigned short* __restrict__ Wrk,
                                              float* __restrict__ bs_sum) {
    int g = blockIdx.x * 256 + threadIdx.x;
    if (g < SC * KTOT) {
        int i = g >> 13, r = g & 8191;      // 8192 = 256 oc * 32 c
        int oc = r >> 5, c = r & 31;
        Wsk2[g] = f2bf_bits(Ws[(i * SC + oc) * RC + c]);
        return;
    }
    g -= SC * KTOT;
    if (g < OUTC * SC) { Wfk[g] = f2bf_bits(Wf[g]); return; }
    g -= OUTC * SC;
    if (g < NL * 1024) {
        int i = g >> 10, r = g & 1023;
        int o = r >> 5, c = r & 31;
        Wd1k[g] = f2bf_bits(Wd[((i * DC + o) * RC + c) * 2 + 1]);
        return;
    }
    g -= NL * 1024;
    if (g < NL * 1024) {
        int i = g >> 10, r = g & 1023;
        int o = r >> 5, c = r & 31;
        Wd0k[g] = f2bf_bits(Wd[((i * DC + o) * RC + c) * 2 + 0]);
        return;
    }
    g -= NL * 1024;
    if (g < NL * 1024) { Wrk[g] = f2bf_bits(Wr[g]); return; }
    g -= NL * 1024;
    if (g < SC) {
        float s = 0.f;
        for (int i = 0; i < NL; ++i) s += bs[i * SC + g];
        bs_sum[g] = s;
    }
}

// ---------- start conv -> bf16 stream slot 0 ----------
__global__ __launch_bounds__(256) void k_start(const float* __restrict__ x,
                                               const float* __restrict__ Wst,
                                               const float* __restrict__ bst,
                                               unsigned short* __restrict__ h0) {
    int g = blockIdx.x * 256 + threadIdx.x;   // bt
    float xv = x[g];
    unsigned u[16];
#pragma unroll
    for (int q = 0; q < 16; ++q) {
        float a = Wst[2 * q] * xv + bst[2 * q];
        float b = Wst[2 * q + 1] * xv + bst[2 * q + 1];
        u[q] = pack2(a, b);
    }
    unsigned short* op = h0 + (size_t)g * 32;
#pragma unroll
    for (int q = 0; q < 4; ++q) *(uint4*)&op[q * 8] = *(uint4*)&u[q * 4];
}

// ---------- one WaveNet layer: MFMA, bf16 stream (R8 verbatim) ----------
__global__ __launch_bounds__(256, 4) void k_layer(const unsigned short* __restrict__ hprev,
                                                  unsigned short* __restrict__ hnext,
                                                  const unsigned short* __restrict__ Wd1k,
                                                  const unsigned short* __restrict__ Wd0k,
                                                  const unsigned short* __restrict__ Wrk,
                                                  const float* __restrict__ bd,
                                                  const float* __restrict__ br,
                                                  int d) {
    __shared__ unsigned short zbuf[4][32 * 40];
    int lane = threadIdx.x & 63;
    int wq = threadIdx.x >> 6;
    int lr = lane & 15, lg = lane >> 4;
    int btb = blockIdx.x * 128 + wq * 32;
    unsigned short* zp = &zbuf[wq][0];

    bf16x8 wd1[2], wd0[2], wr[2];
#pragma unroll
    for (int m = 0; m < 2; ++m) {
        int ao = (m * 16 + lr) * 32 + 8 * lg;
        wd1[m] = *(const bf16x8*)(Wd1k + ao);
        wd0[m] = *(const bf16x8*)(Wd0k + ao);
        wr[m]  = *(const bf16x8*)(Wrk + ao);
    }

    bf16x8 hc[2], hs[2];
    uint2 hcc[2][2];
#pragma unroll
    for (int n = 0; n < 2; ++n) {
        int bt = btb + n * 16 + lr;
        int t = bt & (T_LEN - 1);
        const unsigned short* hp = hprev + (size_t)bt * 32;
        hc[n] = *(const bf16x8*)(hp + 8 * lg);
        int bts = (t >= d) ? (bt - d) : bt;
        bf16x8 v = *(const bf16x8*)(hprev + (size_t)bts * 32 + 8 * lg);
        if (t < d) v = (bf16x8){0, 0, 0, 0, 0, 0, 0, 0};
        hs[n] = v;
#pragma unroll
        for (int m = 0; m < 2; ++m) hcc[n][m] = *(const uint2*)(hp + m * 16 + 4 * lg);
    }

    f32x4 zac[2][2];
#pragma unroll
    for (int m = 0; m < 2; ++m)
#pragma unroll
        for (int n = 0; n < 2; ++n) {
            f32x4 a = __builtin_amdgcn_mfma_f32_16x16x32_bf16(wd0[m], hs[n], (f32x4){0.f, 0.f, 0.f, 0.f}, 0, 0, 0);
            zac[m][n] = __builtin_amdgcn_mfma_f32_16x16x32_bf16(wd1[m], hc[n], a, 0, 0, 0);
        }

#pragma unroll
    for (int m = 0; m < 2; ++m) {
        float4 bdv = *(const float4*)(bd + m * 16 + 4 * lg);
#pragma unroll
        for (int n = 0; n < 2; ++n) {
            int rbt = n * 16 + lr;
            float z0 = ftanh(zac[m][n][0] + bdv.x);
            float z1 = ftanh(zac[m][n][1] + bdv.y);
            float z2 = ftanh(zac[m][n][2] + bdv.z);
            float z3 = ftanh(zac[m][n][3] + bdv.w);
            uint2 u;
            u.x = pack2(z0, z1);
            u.y = pack2(z2, z3);
            *(uint2*)(zp + rbt * 40 + m * 16 + 4 * lg) = u;
        }
    }

    f32x4 racc[2][2];
#pragma unroll
    for (int n = 0; n < 2; ++n) {
        int rbt = n * 16 + lr;
        bf16x8 zb = *(const bf16x8*)(zp + rbt * 40 + 8 * lg);
#pragma unroll
        for (int m = 0; m < 2; ++m)
            racc[m][n] = __builtin_amdgcn_mfma_f32_16x16x32_bf16(wr[m], zb, (f32x4){0.f, 0.f, 0.f, 0.f}, 0, 0, 0);
    }

#pragma unroll
    for (int m = 0; m < 2; ++m) {
        float4 brv = *(const float4*)(br + m * 16 + 4 * lg);
#pragma unroll
        for (int n = 0; n < 2; ++n) {
            int bt = btb + n * 16 + lr;
            float h0 = bflo(hcc[n][m].x) + racc[m][n][0] + brv.x;
            float h1 = bfhi(hcc[n][m].x) + racc[m][n][1] + brv.y;
            float h2 = bflo(hcc[n][m].y) + racc[m][n][2] + brv.z;
            float h3 = bfhi(hcc[n][m].y) + racc[m][n][3] + brv.w;
            uint2 u;
            u.x = pack2(h0, h1);
            u.y = pack2(h2, h3);
            *(uint2*)(hnext + (size_t)bt * 32 + m * 16 + 4 * lg) = u;
        }
    }
}

// ---------- fused skip + final GEMM (R8 v4 structure; K-loop REVERSED: slot 39 -> 0) ----------
// Reversal reads the most-recently-written hist slots first, while they are still
// L3-resident, before the 335+134 MB stream evicts them (LRU). Sum is commutative.
__global__ __launch_bounds__(512, 4) void k_skipfinal(const unsigned short* __restrict__ hist,
                                                      const unsigned short* __restrict__ Wsk2,
                                                      const unsigned short* __restrict__ Wfk,
                                                      const float* __restrict__ bs_sum,
                                                      const float* __restrict__ bfv,
                                                      float* __restrict__ outp) {
    __shared__ char smem[65536];   // ring: 2 x 24 KB ; phase-2 sk tile 64 KB overlays
    const int tid = threadIdx.x;
    const int lane = tid & 63, wq = tid >> 6;
    const int lr = lane & 15, lg = lane >> 4;
    const int wm = wq & 3, wn = wq >> 2;
    const int bt0 = blockIdx.x * BTW;
    const char* histb = (const char*)hist;
    const char* Wsb = (const char*)Wsk2;
    lds_char* smem3 = (lds_char*)smem;

    int asrc[2], bsrc;
#pragma unroll
    for (int p = 0; p < 2; ++p) asrc[p] = swz(p * 8192 + tid * 16);
    {
        int D = tid * 16;
        bsrc = bt0 * 64 + swz(D);
    }

    // stage(k) loads LAYER (NL-1-k) for both A and B (reversed traversal)
    auto stage = [&](int k) {
        int sl = NL - 1 - k;
        char* base = smem + (k & 1) * RING;
#pragma unroll
        for (int p = 0; p < 2; ++p)
            __builtin_amdgcn_global_load_lds((const glb_u32*)(Wsb + (size_t)sl * 16384 + asrc[p]),
                                             (lds_u32*)(base + p * 8192 + tid * 16), 16, 0, 0);
        __builtin_amdgcn_global_load_lds((const glb_u32*)(histb + (size_t)sl * SLOTB + bsrc),
                                         (lds_u32*)(base + 16384 + tid * 16), 16, 0, 0);
    };

    f32x4 acc[4][4];
#pragma unroll
    for (int m = 0; m < 4; ++m)
#pragma unroll
        for (int n = 0; n < 4; ++n) acc[m][n] = (f32x4){0.f, 0.f, 0.f, 0.f};

    const int cswz = (lg * 16) ^ (((lr >> 1) & 3) << 4);
    const int arow = wm * 64 + lr;
    const int brow = wn * 64 + lr;

    stage(0);
    stage(1);

#pragma unroll
    for (int i = 0; i < NL; ++i) {
        if (i >= 1 && i + 1 < NL) stage(i + 1);
        if (i + 1 < NL) asm volatile("s_waitcnt vmcnt(3)" ::: "memory");
        else            asm volatile("s_waitcnt vmcnt(0)" ::: "memory");
        __builtin_amdgcn_s_barrier();

        lds_char* Ab = smem3 + (i & 1) * RING;
        lds_char* Bb = Ab + 16384;
        bf16x8 af0, af1, af2, af3, bb0, bb1, bb2, bb3;
        asm volatile("ds_read_b128 %0, %1" : "=v"(af0) : "v"(Ab + (arow + 0) * 64 + cswz));
        asm volatile("ds_read_b128 %0, %1" : "=v"(af1) : "v"(Ab + (arow + 16) * 64 + cswz));
        asm volatile("ds_read_b128 %0, %1" : "=v"(af2) : "v"(Ab + (arow + 32) * 64 + cswz));
        asm volatile("ds_read_b128 %0, %1" : "=v"(af3) : "v"(Ab + (arow + 48) * 64 + cswz));
        asm volatile("ds_read_b128 %0, %1" : "=v"(bb0) : "v"(Bb + (brow + 0) * 64 + cswz));
        asm volatile("ds_read_b128 %0, %1" : "=v"(bb1) : "v"(Bb + (brow + 16) * 64 + cswz));
        asm volatile("ds_read_b128 %0, %1" : "=v"(bb2) : "v"(Bb + (brow + 32) * 64 + cswz));
        asm volatile("ds_read_b128 %0, %1" : "=v"(bb3) : "v"(Bb + (brow + 48) * 64 + cswz));
        asm volatile("s_waitcnt lgkmcnt(0)" ::: "memory");
        __builtin_amdgcn_sched_barrier(0);

        acc[0][0] = __builtin_amdgcn_mfma_f32_16x16x32_bf16(af0, bb0, acc[0][0], 0, 0, 0);
        acc[1][0] = __builtin_amdgcn_mfma_f32_16x16x32_bf16(af1, bb0, acc[1][0], 0, 0, 0);
        acc[2][0] = __builtin_amdgcn_mfma_f32_16x16x32_bf16(af2, bb0, acc[2][0], 0, 0, 0);
        acc[3][0] = __builtin_amdgcn_mfma_f32_16x16x32_bf16(af3, bb0, acc[3][0], 0, 0, 0);
        acc[0][1] = __builtin_amdgcn_mfma_f32_16x16x32_bf16(af0, bb1, acc[0][1], 0, 0, 0);
        acc[1][1] = __builtin_amdgcn_mfma_f32_16x16x32_bf16(af1, bb1, acc[1][1], 0, 0, 0);
        acc[2][1] = __builtin_amdgcn_mfma_f32_16x16x32_bf16(af2, bb1, acc[2][1], 0, 0, 0);
        acc[3][1] = __builtin_amdgcn_mfma_f32_16x16x32_bf16(af3, bb1, acc[3][1], 0, 0, 0);
        acc[0][2] = __builtin_amdgcn_mfma_f32_16x16x32_bf16(af0, bb2, acc[0][2], 0, 0, 0);
        acc[1][2] = __builtin_amdgcn_mfma_f32_16x16x32_bf16(af1, bb2, acc[1][2], 0, 0, 0);
        acc[2][2] = __builtin_amdgcn_mfma_f32_16x16x32_bf16(af2, bb2, acc[2][2], 0, 0, 0);
        acc[3][2] = __builtin_amdgcn_mfma_f32_16x16x32_bf16(af3, bb2, acc[3][2], 0, 0, 0);
        acc[0][3] = __builtin_amdgcn_mfma_f32_16x16x32_bf16(af0, bb3, acc[0][3], 0, 0, 0);
        acc[1][3] = __builtin_amdgcn_mfma_f32_16x16x32_bf16(af1, bb3, acc[1][3], 0, 0, 0);
        acc[2][3] = __builtin_amdgcn_mfma_f32_16x16x32_bf16(af2, bb3, acc[2][3], 0, 0, 0);
        acc[3][3] = __builtin_amdgcn_mfma_f32_16x16x32_bf16(af3, bb3, acc[3][3], 0, 0, 0);
        __builtin_amdgcn_s_barrier();
    }
    __syncthreads();

    char* skb = smem;
#pragma unroll
    for (int m = 0; m < 4; ++m) {
        int oc0 = wm * 64 + m * 16 + lg * 4;
        float c0 = bs_sum[oc0], c1 = bs_sum[oc0 + 1], c2 = bs_sum[oc0 + 2], c3 = bs_sum[oc0 + 3];
#pragma unroll
        for (int n = 0; n < 4; ++n) {
            int bt = wn * 64 + n * 16 + lr;
            f32x4 v = acc[m][n];
            uint2 u;
            u.x = pack2(fmaxf(v[0] + c0, 0.f), fmaxf(v[1] + c1, 0.f));
            u.y = pack2(fmaxf(v[2] + c2, 0.f), fmaxf(v[3] + c3, 0.f));
            int L = bt * 512 + oc0 * 2;
            *(uint2*)(skb + (L ^ ((bt & 7) << 4))) = u;
        }
    }
    __syncthreads();

    f32x4 acc2[4][4];
#pragma unroll
    for (int m = 0; m < 4; ++m)
#pragma unroll
        for (int n = 0; n < 4; ++n) acc2[m][n] = (f32x4){0.f, 0.f, 0.f, 0.f};

    const unsigned short* Fb = Wfk + (size_t)(wm * 64 + lr) * SC + 8 * lg;

#pragma unroll
    for (int kk = 0; kk < SC / 32; ++kk) {
        bf16x8 fa[4];
#pragma unroll
        for (int m = 0; m < 4; ++m) fa[m] = *(const bf16x8*)(Fb + (size_t)m * 16 * SC + kk * 32);
        bf16x8 sbv[4];
#pragma unroll
        for (int n = 0; n < 4; ++n) {
            int bt = wn * 64 + n * 16 + lr;
            int L = bt * 512 + kk * 64 + lg * 16;
            sbv[n] = *(const bf16x8*)(skb + (L ^ ((bt & 7) << 4)));
        }
#pragma unroll
        for (int m = 0; m < 4; ++m)
#pragma unroll
            for (int n = 0; n < 4; ++n)
                acc2[m][n] = __builtin_amdgcn_mfma_f32_16x16x32_bf16(fa[m], sbv[n], acc2[m][n], 0, 0, 0);
    }

    int b2 = bt0 >> 15;
    int t0 = bt0 & (T_LEN - 1);
#pragma unroll
    for (int m = 0; m < 4; ++m) {
        int o0 = wm * 64 + m * 16 + lg * 4;
        float q0 = bfv[o0], q1 = bfv[o0 + 1], q2 = bfv[o0 + 2], q3 = bfv[o0 + 3];
#pragma unroll
        for (int n = 0; n < 4; ++n) {
            int t = t0 + wn * 64 + n * 16 + lr;
            f32x4 v = acc2[m][n];
            outp[((size_t)(b2 * OUTC + o0 + 0) << 15) + t] = v[0] + q0;
            outp[((size_t)(b2 * OUTC + o0 + 1) << 15) + t] = v[1] + q1;
            outp[((size_t)(b2 * OUTC + o0 + 2) << 15) + t] = v[2] + q2;
            outp[((size_t)(b2 * OUTC + o0 + 3) << 15) + t] = v[3] + q3;
        }
    }
}

extern "C" void kernel_launch(void* const* d_in, const int* in_sizes, int n_in,
                              void* d_out, int out_size, void* d_ws, size_t ws_size,
                              hipStream_t stream) {
    const float* x       = (const float*)d_in[0];
    const float* W_start = (const float*)d_in[1];
    const float* b_start = (const float*)d_in[2];
    const float* Wd      = (const float*)d_in[3];
    const float* bd      = (const float*)d_in[4];
    const float* Wr      = (const float*)d_in[5];
    const float* br      = (const float*)d_in[6];
    const float* Ws      = (const float*)d_in[7];
    const float* bs      = (const float*)d_in[8];
    const float* Wf      = (const float*)d_in[9];
    const float* bfv     = (const float*)d_in[10];

    char* wsb = (char*)d_ws;
    unsigned short* Wsk2 = (unsigned short*)(wsb);                      // 655360 B
    unsigned short* Wfk  = (unsigned short*)(wsb + 655360);             // 131072 B
    unsigned short* Wd1k = (unsigned short*)(wsb + 786432);             // 81920 B
    unsigned short* Wd0k = (unsigned short*)(wsb + 868352);             // 81920 B
    unsigned short* Wrk  = (unsigned short*)(wsb + 950272);             // 81920 B
    float*          bs_sum = (float*)(wsb + 1032192);                   // 1024 B
    char* S1 = wsb + (1 << 20);            // stream slots 1..40 (= hist layers 0..39)
    char* X  = S1 + 40 * SLOTB;            // slot 0

    auto slotptr = [&](int i) -> unsigned short* {
        return (unsigned short*)(i == 0 ? X : S1 + (size_t)(i - 1) * SLOTB);
    };

    k_prep<<<(SC * KTOT + OUTC * SC + 3 * NL * 1024 + SC + 255) / 256, 256, 0, stream>>>(
        Ws, Wf, Wd, Wr, bs, Wsk2, Wfk, Wd1k, Wd0k, Wrk, bs_sum);
    k_start<<<NBT / 256, 256, 0, stream>>>(x, W_start, b_start, slotptr(0));

    for (int i = 0; i < NL; ++i) {
        int d = 1 << (i % 10);
        k_layer<<<NBT / 128, 256, 0, stream>>>(slotptr(i), slotptr(i + 1),
                                               Wd1k + i * 1024, Wd0k + i * 1024, Wrk + i * 1024,
                                               bd + i * DC, br + i * RC, d);
    }

    k_skipfinal<<<NBT / BTW, 512, 0, stream>>>((unsigned short*)S1, Wsk2, Wfk, bs_sum, bfv, (float*)d_out);
}